// Round 1
// baseline (548.634 us; speedup 1.0000x reference)
//
#include <hip/hip_runtime.h>

// AdaPool2D: 2x2 stride-2 window, blend of exp-softmax pooling and
// Dice-Sorensen-softmax pooling.
//   inputs: [B=32, W=224, H=224, C=64] fp32 (C contiguous innermost)
//   mask:   [1] fp32 blend scalar
//   out:    [B, 112, 112, 64] fp32
//
// Memory-bound: 411 MB in + 103 MB out, every input element read exactly once.
// One thread = one (b,wo,ho) spatial output x 4 channels (float4).

constexpr int Bn = 32;
constexpr int Wd = 224;
constexpr int Hd = 224;
constexpr int Cd = 64;
constexpr int Wo = 112;
constexpr int Ho = 112;
constexpr int HC = Hd * Cd;                       // 14336: W-row stride in floats
constexpr int TOTAL4 = Bn * Wo * Ho * (Cd / 4);   // 6,422,528 float4 work items

__global__ __launch_bounds__(256)
void adapool2d_kernel(const float* __restrict__ in,
                      const float* __restrict__ mask,
                      float* __restrict__ out) {
    int i = blockIdx.x * 256 + threadIdx.x;
    if (i >= TOTAL4) return;

    const float m  = mask[0];          // uniform -> scalar load
    const float m1 = 1.0f - m;

    // i = ((b*Wo + wo)*Ho + ho)*16 + c4   (matches output linear order)
    int c4 = (i & 15) * 4;
    int t  = i >> 4;
    int ho = t % Ho;
    t      = t / Ho;
    int wo = t % Wo;
    int b  = t / Wo;

    const float* p = in + (size_t)(b * Wd + 2 * wo) * HC + (2 * ho) * Cd + c4;
    float4 v00 = *reinterpret_cast<const float4*>(p);            // (2wo  , 2ho  )
    float4 v01 = *reinterpret_cast<const float4*>(p + Cd);       // (2wo  , 2ho+1)
    float4 v10 = *reinterpret_cast<const float4*>(p + HC);       // (2wo+1, 2ho  )
    float4 v11 = *reinterpret_cast<const float4*>(p + HC + Cd);  // (2wo+1, 2ho+1)

    float q0[4] = {v00.x, v00.y, v00.z, v00.w};
    float q1[4] = {v01.x, v01.y, v01.z, v01.w};
    float q2[4] = {v10.x, v10.y, v10.z, v10.w};
    float q3[4] = {v11.x, v11.y, v11.z, v11.w};
    float r[4];

#pragma unroll
    for (int k = 0; k < 4; ++k) {
        float a  = q0[k], bb = q1[k], cc = q2[k], dd = q3[k];

        // exponential-maximum pooling: sum(p * softmax(p))
        float ea = __expf(a), eb = __expf(bb), ec = __expf(cc), ed = __expf(dd);
        float inv_se = __builtin_amdgcn_rcpf(ea + eb + ec + ed);
        float em = (a * ea + bb * eb + cc * ec + dd * ed) * inv_se;

        // eDSCW pooling: dsc = 2*avg*p / (avg^2 + p^2), softmax over window
        float avg  = 0.25f * (a + bb + cc + dd);
        float avg2 = avg * avg;
        float ta   = 2.0f * avg;
        float da = ta * a  * __builtin_amdgcn_rcpf(avg2 + a  * a);
        float db = ta * bb * __builtin_amdgcn_rcpf(avg2 + bb * bb);
        float dc = ta * cc * __builtin_amdgcn_rcpf(avg2 + cc * cc);
        float de = ta * dd * __builtin_amdgcn_rcpf(avg2 + dd * dd);
        float fa = __expf(da), fb = __expf(db), fc = __expf(dc), fd = __expf(de);
        float inv_sd = __builtin_amdgcn_rcpf(fa + fb + fc + fd);
        float dp = (a * fa + bb * fb + cc * fc + dd * fd) * inv_sd;

        r[k] = em * m + dp * m1;
    }

    float4 o = make_float4(r[0], r[1], r[2], r[3]);
    reinterpret_cast<float4*>(out)[i] = o;
}

extern "C" void kernel_launch(void* const* d_in, const int* in_sizes, int n_in,
                              void* d_out, int out_size, void* d_ws, size_t ws_size,
                              hipStream_t stream) {
    const float* in   = (const float*)d_in[0];
    const float* mask = (const float*)d_in[1];
    float* out        = (float*)d_out;

    constexpr int threads = 256;
    constexpr int blocks  = (TOTAL4 + threads - 1) / threads;  // 25088
    adapool2d_kernel<<<blocks, threads, 0, stream>>>(in, mask, out);
}